// Round 1
// baseline (1963.165 us; speedup 1.0000x reference)
//
#include <hip/hip_runtime.h>
#include <hip/hip_bf16.h>
#include <stdint.h>

#define N_TOK 4096
#define DIM   1024
#define NEXP  8
#define HID   4096

#define BM 128
#define BN 128
#define BK 32
#define KPAD 40   // bf16 elems per LDS row (k), padded for bank spread

typedef __attribute__((ext_vector_type(8))) __bf16 bf16x8;
typedef __attribute__((ext_vector_type(4))) float f32x4;
typedef __attribute__((ext_vector_type(4))) unsigned int uint4v;

// ws layout (bytes)
#define WS_CNT 0
#define WS_TOK 4096
#define WS_WT  (WS_TOK + NEXP * N_TOK * 4)
#define WS_H   (WS_WT + NEXP * N_TOK * 4)
// WS_H size = 2*N_TOK rows * HID * 2B = 67,108,864

__device__ __forceinline__ unsigned short f2bf(float f) {
  unsigned int u = __float_as_uint(f);
  u += 0x7fffu + ((u >> 16) & 1u);   // round-to-nearest-even
  return (unsigned short)(u >> 16);
}

// ---------------- gating: fp32 logits, softmax, top-2, scatter ----------------
__global__ __launch_bounds__(256) void moe_gate(
    const float* __restrict__ x, const float* __restrict__ Wg,
    const float* __restrict__ bg,
    int* __restrict__ cnt, int* __restrict__ tok_of, float* __restrict__ wt_of)
{
  const int t    = blockIdx.x * 4 + (threadIdx.x >> 6);
  const int lane = threadIdx.x & 63;

  float p[NEXP];
#pragma unroll
  for (int e = 0; e < NEXP; ++e) p[e] = 0.f;

  const float* xr = x + (size_t)t * DIM;
  for (int i = lane; i < DIM; i += 64) {
    float xv = xr[i];
    float4 w0 = *(const float4*)(Wg + i * NEXP);
    float4 w1 = *(const float4*)(Wg + i * NEXP + 4);
    p[0] += xv * w0.x; p[1] += xv * w0.y; p[2] += xv * w0.z; p[3] += xv * w0.w;
    p[4] += xv * w1.x; p[5] += xv * w1.y; p[6] += xv * w1.z; p[7] += xv * w1.w;
  }
#pragma unroll
  for (int e = 0; e < NEXP; ++e) {
    float v = p[e];
#pragma unroll
    for (int off = 32; off > 0; off >>= 1) v += __shfl_xor(v, off);
    p[e] = v + bg[e];
  }
  if (lane == 0) {
    float m = p[0];
#pragma unroll
    for (int e = 1; e < NEXP; ++e) m = fmaxf(m, p[e]);
    float g[NEXP], s = 0.f;
#pragma unroll
    for (int e = 0; e < NEXP; ++e) { g[e] = expf(p[e] - m); s += g[e]; }
    float inv = 1.f / s;
#pragma unroll
    for (int e = 0; e < NEXP; ++e) g[e] *= inv;

    int e0 = 0; float v0 = g[0];
#pragma unroll
    for (int e = 1; e < NEXP; ++e) if (g[e] > v0) { v0 = g[e]; e0 = e; }
    int e1 = -1; float v1 = -1.f;
#pragma unroll
    for (int e = 0; e < NEXP; ++e) if (e != e0 && g[e] > v1) { v1 = g[e]; e1 = e; }

    int s0 = atomicAdd(cnt + e0, 1);
    tok_of[e0 * N_TOK + s0] = t;
    wt_of[e0 * N_TOK + s0] = v0;
    int s1 = atomicAdd(cnt + e1, 1);
    tok_of[e1 * N_TOK + s1] = t;
    wt_of[e1 * N_TOK + s1] = v1;
  }
}

// ---------------- GEMM1: h = relu(gather(x) @ W1[e] + b1[e]) -> bf16 ----------------
__global__ __launch_bounds__(256) void moe_ffn1(
    const float* __restrict__ x, const float* __restrict__ W1,
    const float* __restrict__ b1, const int* __restrict__ cnt,
    const int* __restrict__ tok_of, unsigned short* __restrict__ h)
{
  const int e  = blockIdx.z;
  const int mb = blockIdx.x;
  const int nb = blockIdx.y;
  const int cnte = cnt[e];
  const int m0 = mb * BM;
  if (m0 >= cnte) return;

  int base = 0;
  for (int j = 0; j < NEXP; ++j) if (j < e) base += cnt[j];

  __shared__ unsigned short As[BM][KPAD];
  __shared__ unsigned short Bs[BN][KPAD];
  __shared__ int toks[BM];

  const int tid = threadIdx.x;
  if (tid < BM) {
    int slot = m0 + tid;
    toks[tid] = (slot < cnte) ? tok_of[e * N_TOK + slot] : -1;
  }
  __syncthreads();

  const int lane = tid & 63;
  const int wv = tid >> 6;
  const int wr = wv >> 1, wc = wv & 1;
  const int fr = lane & 15;
  const int k8 = (lane >> 4) * 8;
  const int r4 = (lane >> 4) * 4;

  f32x4 acc[4][4];
#pragma unroll
  for (int m = 0; m < 4; ++m)
#pragma unroll
    for (int n = 0; n < 4; ++n) acc[m][n] = (f32x4)(0.f);

  const int arow = tid & (BM - 1);
  const int akg  = tid >> 7;   // 0/1
  const int bcol = tid & (BN - 1);
  const int bkg  = tid >> 7;
  const int atok = toks[arow];
  const float* Wb = W1 + (size_t)e * DIM * HID + (size_t)nb * BN;

  for (int k0 = 0; k0 < DIM; k0 += BK) {
    // ---- stage A (gathered token rows), fp32 -> bf16 ----
    float av[16];
    if (atok >= 0) {
      const float* srcp = x + (size_t)atok * DIM + k0 + akg * 16;
#pragma unroll
      for (int q = 0; q < 4; ++q) {
        float4 v = *(const float4*)(srcp + q * 4);
        av[q*4+0] = v.x; av[q*4+1] = v.y; av[q*4+2] = v.z; av[q*4+3] = v.w;
      }
    } else {
#pragma unroll
      for (int q = 0; q < 16; ++q) av[q] = 0.f;
    }
    {
      union { unsigned short u[8]; uint4v v; } pka, pkb;
#pragma unroll
      for (int q = 0; q < 8; ++q) pka.u[q] = f2bf(av[q]);
#pragma unroll
      for (int q = 0; q < 8; ++q) pkb.u[q] = f2bf(av[8 + q]);
      *(uint4v*)&As[arow][akg * 16]     = pka.v;
      *(uint4v*)&As[arow][akg * 16 + 8] = pkb.v;
    }
    // ---- stage B transposed: Bs[col][k], coalesced global rows ----
#pragma unroll
    for (int p = 0; p < 4; ++p) {
      int kk = bkg * 4 + p * 8;
      float q0 = Wb[(size_t)(k0 + kk + 0) * HID + bcol];
      float q1 = Wb[(size_t)(k0 + kk + 1) * HID + bcol];
      float q2 = Wb[(size_t)(k0 + kk + 2) * HID + bcol];
      float q3 = Wb[(size_t)(k0 + kk + 3) * HID + bcol];
      union { unsigned short u[4]; uint2 v; } pk;
      pk.u[0] = f2bf(q0); pk.u[1] = f2bf(q1); pk.u[2] = f2bf(q2); pk.u[3] = f2bf(q3);
      *(uint2*)&Bs[bcol][kk] = pk.v;
    }
    __syncthreads();

    bf16x8 af[4], bfr[4];
#pragma unroll
    for (int m = 0; m < 4; ++m)
      af[m] = *(const bf16x8*)&As[wr * 64 + m * 16 + fr][k8];
#pragma unroll
    for (int n = 0; n < 4; ++n)
      bfr[n] = *(const bf16x8*)&Bs[wc * 64 + n * 16 + fr][k8];
#pragma unroll
    for (int m = 0; m < 4; ++m)
#pragma unroll
      for (int n = 0; n < 4; ++n)
        acc[m][n] = __builtin_amdgcn_mfma_f32_16x16x32_bf16(af[m], bfr[n], acc[m][n], 0, 0, 0);
    __syncthreads();
  }

  // ---- epilogue: relu(acc + b1) -> bf16 h rows ----
#pragma unroll
  for (int n = 0; n < 4; ++n) {
    const int colg = nb * BN + wc * 64 + n * 16 + fr;
    const float bias = b1[e * HID + colg];
#pragma unroll
    for (int m = 0; m < 4; ++m) {
#pragma unroll
      for (int j = 0; j < 4; ++j) {
        int slot = m0 + wr * 64 + m * 16 + r4 + j;
        if (slot < cnte) {
          float v = acc[m][n][j] + bias;
          v = fmaxf(v, 0.f);
          h[(size_t)(base + slot) * HID + colg] = f2bf(v);
        }
      }
    }
  }
}

// ---------------- GEMM2: out += w * (h @ W2[e] + b2[e]) ----------------
__global__ __launch_bounds__(256) void moe_ffn2(
    const unsigned short* __restrict__ h, const float* __restrict__ W2,
    const float* __restrict__ b2, const int* __restrict__ cnt,
    const int* __restrict__ tok_of, const float* __restrict__ wt_of,
    float* __restrict__ out)
{
  const int e  = blockIdx.z;
  const int mb = blockIdx.x;
  const int nb = blockIdx.y;
  const int cnte = cnt[e];
  const int m0 = mb * BM;
  if (m0 >= cnte) return;

  int base = 0;
  for (int j = 0; j < NEXP; ++j) if (j < e) base += cnt[j];

  __shared__ unsigned short As[BM][KPAD];
  __shared__ unsigned short Bs[BN][KPAD];
  __shared__ int   toks[BM];
  __shared__ float wts[BM];

  const int tid = threadIdx.x;
  if (tid < BM) {
    int slot = m0 + tid;
    if (slot < cnte) {
      toks[tid] = tok_of[e * N_TOK + slot];
      wts[tid]  = wt_of[e * N_TOK + slot];
    } else {
      toks[tid] = 0; wts[tid] = 0.f;
    }
  }
  __syncthreads();

  const int lane = tid & 63;
  const int wv = tid >> 6;
  const int wr = wv >> 1, wc = wv & 1;
  const int fr = lane & 15;
  const int k8 = (lane >> 4) * 8;
  const int r4 = (lane >> 4) * 4;

  f32x4 acc[4][4];
#pragma unroll
  for (int m = 0; m < 4; ++m)
#pragma unroll
    for (int n = 0; n < 4; ++n) acc[m][n] = (f32x4)(0.f);

  const int arow = tid & (BM - 1);
  const int akg  = tid >> 7;
  const int bcol = tid & (BN - 1);
  const int bkg  = tid >> 7;
  const int aslot = m0 + arow;
  const float* Wb = W2 + (size_t)e * HID * DIM + (size_t)nb * BN;

  for (int k0 = 0; k0 < HID; k0 += BK) {
    // ---- stage A from bf16 h (already compact) ----
    if (aslot < cnte) {
      const uint4v* srcp = (const uint4v*)(h + (size_t)(base + aslot) * HID + k0 + akg * 16);
      *(uint4v*)&As[arow][akg * 16]     = srcp[0];
      *(uint4v*)&As[arow][akg * 16 + 8] = srcp[1];
    } else {
      uint4v z = (uint4v)(0u);
      *(uint4v*)&As[arow][akg * 16]     = z;
      *(uint4v*)&As[arow][akg * 16 + 8] = z;
    }
    // ---- stage B transposed ----
#pragma unroll
    for (int p = 0; p < 4; ++p) {
      int kk = bkg * 4 + p * 8;
      float q0 = Wb[(size_t)(k0 + kk + 0) * DIM + bcol];
      float q1 = Wb[(size_t)(k0 + kk + 1) * DIM + bcol];
      float q2 = Wb[(size_t)(k0 + kk + 2) * DIM + bcol];
      float q3 = Wb[(size_t)(k0 + kk + 3) * DIM + bcol];
      union { unsigned short u[4]; uint2 v; } pk;
      pk.u[0] = f2bf(q0); pk.u[1] = f2bf(q1); pk.u[2] = f2bf(q2); pk.u[3] = f2bf(q3);
      *(uint2*)&Bs[bcol][kk] = pk.v;
    }
    __syncthreads();

    bf16x8 af[4], bfr[4];
#pragma unroll
    for (int m = 0; m < 4; ++m)
      af[m] = *(const bf16x8*)&As[wr * 64 + m * 16 + fr][k8];
#pragma unroll
    for (int n = 0; n < 4; ++n)
      bfr[n] = *(const bf16x8*)&Bs[wc * 64 + n * 16 + fr][k8];
#pragma unroll
    for (int m = 0; m < 4; ++m)
#pragma unroll
      for (int n = 0; n < 4; ++n)
        acc[m][n] = __builtin_amdgcn_mfma_f32_16x16x32_bf16(af[m], bfr[n], acc[m][n], 0, 0, 0);
    __syncthreads();
  }

  // ---- epilogue: weighted bias + scatter-add to out ----
#pragma unroll
  for (int n = 0; n < 4; ++n) {
    const int colg = nb * BN + wc * 64 + n * 16 + fr;
    const float bias = b2[e * DIM + colg];
#pragma unroll
    for (int m = 0; m < 4; ++m) {
#pragma unroll
      for (int j = 0; j < 4; ++j) {
        int rl = wr * 64 + m * 16 + r4 + j;
        int slot = m0 + rl;
        if (slot < cnte) {
          float v = (acc[m][n][j] + bias) * wts[rl];
          atomicAdd(out + (size_t)toks[rl] * DIM + colg, v);
        }
      }
    }
  }
}

extern "C" void kernel_launch(void* const* d_in, const int* in_sizes, int n_in,
                              void* d_out, int out_size, void* d_ws, size_t ws_size,
                              hipStream_t stream) {
  const float* x  = (const float*)d_in[0];
  const float* Wg = (const float*)d_in[1];
  const float* bg = (const float*)d_in[2];
  const float* W1 = (const float*)d_in[3];
  const float* b1 = (const float*)d_in[4];
  const float* W2 = (const float*)d_in[5];
  const float* b2 = (const float*)d_in[6];
  float* out = (float*)d_out;

  char* ws = (char*)d_ws;
  int*            cnt    = (int*)(ws + WS_CNT);
  int*            tok_of = (int*)(ws + WS_TOK);
  float*          wt_of  = (float*)(ws + WS_WT);
  unsigned short* h      = (unsigned short*)(ws + WS_H);

  hipMemsetAsync(cnt, 0, NEXP * sizeof(int), stream);
  hipMemsetAsync(out, 0, (size_t)out_size * sizeof(float), stream);

  moe_gate<<<N_TOK / 4, 256, 0, stream>>>(x, Wg, bg, cnt, tok_of, wt_of);
  moe_ffn1<<<dim3(N_TOK / BM, HID / BN, NEXP), 256, 0, stream>>>(x, W1, b1, cnt, tok_of, h);
  moe_ffn2<<<dim3(N_TOK / BM, DIM / BN, NEXP), 256, 0, stream>>>(h, W2, b2, cnt, tok_of, wt_of, out);
}